// Round 2
// baseline (38.756 us; speedup 1.0000x reference)
//
#include <hip/hip_runtime.h>
#include <math.h>

#define BB 2
#define LL 1024
#define DD 256
#define UU 32
#define RPB 4                  // rows per block
#define UNION (128 + RPB - 1)  // 131-row union band
#define KPAD 33                // LDS pad: bank (jru+u)%32 -> 2-way alias = free
#define APAD 132

__device__ __forceinline__ float fast_tanh(float x) {
    // tanh(x) = 1 - 2/(e^{2x}+1); clamp so exp never overflows
    x = fminf(10.0f, fmaxf(-10.0f, x));
    float t = __expf(2.0f * x);
    return 1.0f - 2.0f * __builtin_amdgcn_rcpf(t + 1.0f);
}

// q[row,u] = x[row,:] . Wt[:,u];  k[row,u] = x[row,:] . Wx[:,u] + bh[u]
__global__ __launch_bounds__(256) void qk_kernel(
    const float* __restrict__ x, const float* __restrict__ Wt,
    const float* __restrict__ Wx, const float* __restrict__ bh,
    float* __restrict__ q, float* __restrict__ k)
{
    int tid = threadIdx.x;
    int u = tid & 31;
    int r = tid >> 5;
    int row = blockIdx.x * 8 + r;           // 0 .. B*L-1
    const float* xr = x + (size_t)row * DD;
    float accq = 0.0f;
    float acck = bh[u];
    #pragma unroll 4
    for (int d = 0; d < DD; ++d) {
        float xv = xr[d];
        accq = fmaf(xv, Wt[d * UU + u], accq);
        acck = fmaf(xv, Wx[d * UU + u], acck);
    }
    q[(size_t)row * UU + u] = accq;
    k[(size_t)row * UU + u] = acck;
}

// One block per 4 consecutive output rows. 256 threads.
__global__ __launch_bounds__(256) void attn_kernel(
    const float* __restrict__ x, const float* __restrict__ q,
    const float* __restrict__ k, const float* __restrict__ Wa,
    const float* __restrict__ ba, float* __restrict__ out)
{
    __shared__ float s_k[UNION * KPAD];   // k band, union-indexed
    __shared__ float s_a[RPB * APAD];     // unnormalized e, zero-padded
    __shared__ float s_q[RPB * UU];
    __shared__ float s_wa[UU];
    __shared__ float s_inv[RPB];

    int t = threadIdx.x;
    int blk = blockIdx.x;                 // 0 .. B*L/RPB - 1
    int i0 = (blk * RPB) & (LL - 1);
    int b  = (blk * RPB) >> 10;           // / LL
    int rowbase = b * LL + i0;            // global row index of r=0
    int j0 = i0 - 64;                     // union band start (signed)

    // cooperative staging
    if (t < RPB * UU) s_q[t] = q[(size_t)rowbase * UU + t];
    if (t < UU) s_wa[t] = Wa[t];
    for (int idx = t; idx < RPB * APAD; idx += 256) s_a[idx] = 0.0f;
    for (int idx = t; idx < UNION * UU; idx += 256) {
        int jru = idx >> 5, u = idx & 31;
        int j = j0 + jru;
        if (0 <= j && j < LL)
            s_k[jru * KPAD + u] = k[(size_t)(b * LL + j) * UU + u];
    }
    __syncthreads();

    // Phase 1: 4 rows x 128 band cols = 512 e-entries, 2 per thread
    float ba0 = ba[0];
    #pragma unroll
    for (int it = 0; it < 2; ++it) {
        int idx = t + it * 256;
        int r = idx >> 7, jr = idx & 127;
        int j = j0 + r + jr;              // = i_r - 64 + jr; band cond == j in range
        if (0 <= j && j < LL) {
            int jru = r + jr;             // union-relative index
            const float* kp = &s_k[jru * KPAD];
            const float* qp = &s_q[r * UU];
            float acc = ba0;
            #pragma unroll
            for (int u = 0; u < UU; ++u)
                acc = fmaf(s_wa[u], fast_tanh(qp[u] + kp[u]), acc);
            s_a[r * APAD + jru] = __expf(acc);
        }
    }
    __syncthreads();

    // Phase 2: per-row sums (one wave per row), fold eps + reciprocal
    {
        int r = t >> 6, lane = t & 63;
        float v = 0.0f;
        for (int c = lane; c < APAD; c += 64) v += s_a[r * APAD + c];
        #pragma unroll
        for (int off = 32; off > 0; off >>= 1) v += __shfl_xor(v, off);
        if (lane == 0) s_inv[r] = 1.0f / (v + 1e-7f);
    }
    __syncthreads();

    // Phase 3: j-outer, load x[j,:] once, FMA into 4 row accumulators
    float acc[RPB] = {0.0f, 0.0f, 0.0f, 0.0f};
    const float* xb = x + (size_t)(b * LL) * DD + t;
    for (int jru = 0; jru < UNION; ++jru) {
        int j = j0 + jru;
        if (0 <= j && j < LL) {
            float xv = xb[(size_t)j * DD];
            #pragma unroll
            for (int r = 0; r < RPB; ++r)
                acc[r] = fmaf(s_a[r * APAD + jru], xv, acc[r]);
        }
    }
    #pragma unroll
    for (int r = 0; r < RPB; ++r)
        out[(size_t)(rowbase + r) * DD + t] = acc[r] * s_inv[r];
}

extern "C" void kernel_launch(void* const* d_in, const int* in_sizes, int n_in,
                              void* d_out, int out_size, void* d_ws, size_t ws_size,
                              hipStream_t stream) {
    const float* x  = (const float*)d_in[0];
    const float* Wt = (const float*)d_in[1];
    const float* Wx = (const float*)d_in[2];
    const float* bh = (const float*)d_in[3];
    const float* Wa = (const float*)d_in[4];
    const float* ba = (const float*)d_in[5];
    float* out = (float*)d_out;

    float* q  = (float*)d_ws;                      // B*L*U floats
    float* kk = q + (size_t)BB * LL * UU;          // B*L*U floats

    qk_kernel<<<(BB * LL) / 8, 256, 0, stream>>>(x, Wt, Wx, bh, q, kk);
    attn_kernel<<<(BB * LL) / RPB, 256, 0, stream>>>(x, q, kk, Wa, ba, out);
}

// Round 3
// 26.811 us; speedup vs baseline: 1.4456x; 1.4456x over previous
//
#include <hip/hip_runtime.h>
#include <math.h>

#define BB 2
#define LL 1024
#define DD 256
#define UU 32
#define RPB 4                  // rows per block
#define UNION (128 + RPB - 1)  // 131-row union band
#define KPAD 33                // bank(jru*33+u) = (jru+u)%32 -> max 2-way alias = free
#define APAD 132
#define TPB 1024

__device__ __forceinline__ float fast_tanh(float x) {
    // tanh(x) = 1 - 2/(e^{2x}+1); clamp so exp never overflows
    x = fminf(10.0f, fmaxf(-10.0f, x));
    float t = __expf(2.0f * x);
    return 1.0f - 2.0f * __builtin_amdgcn_rcpf(t + 1.0f);
}

// q[row,u] = x[row,:] . Wt[:,u];  k[row,u] = x[row,:] . Wx[:,u] + bh[u]
__global__ __launch_bounds__(256) void qk_kernel(
    const float* __restrict__ x, const float* __restrict__ Wt,
    const float* __restrict__ Wx, const float* __restrict__ bh,
    float* __restrict__ q, float* __restrict__ k)
{
    int tid = threadIdx.x;
    int u = tid & 31;
    int r = tid >> 5;
    int row = blockIdx.x * 8 + r;           // 0 .. B*L-1
    const float* xr = x + (size_t)row * DD;
    float accq = 0.0f;
    float acck = bh[u];
    #pragma unroll 4
    for (int d = 0; d < DD; ++d) {
        float xv = xr[d];
        accq = fmaf(xv, Wt[d * UU + u], accq);
        acck = fmaf(xv, Wx[d * UU + u], acck);
    }
    q[(size_t)row * UU + u] = accq;
    k[(size_t)row * UU + u] = acck;
}

// One block per 4 consecutive output rows. 1024 threads (16 waves).
// 512 blocks -> 2 blocks/CU -> 32 waves/CU (VGPR <= 64 via launch_bounds).
__global__ __launch_bounds__(TPB, 8) void attn_kernel(
    const float* __restrict__ x, const float* __restrict__ q,
    const float* __restrict__ k, const float* __restrict__ Wa,
    const float* __restrict__ ba, float* __restrict__ out)
{
    __shared__ float s_k[UNION * KPAD];     // k band, union-indexed (17.3 KB)
    __shared__ float s_a[RPB * APAD];       // unnormalized e, zero-padded
    __shared__ float s_q[RPB * UU];
    __shared__ float s_wa[UU];
    __shared__ float s_inv[RPB];
    __shared__ float s_part[4 * RPB * DD];  // per-group partial PV (16 KB)

    int t = threadIdx.x;
    int blk = blockIdx.x;                   // 0 .. B*L/RPB - 1
    int i0 = (blk * RPB) & (LL - 1);
    int b  = (blk * RPB) >> 10;             // / LL
    int rowbase = b * LL + i0;              // global row of r=0
    int j0 = i0 - 64;                       // union band start (signed)

    // cooperative staging
    if (t < RPB * UU) s_q[t] = q[(size_t)rowbase * UU + t];
    if (t < UU) s_wa[t] = Wa[t];
    if (t < RPB * APAD) s_a[t] = 0.0f;
    for (int idx = t; idx < UNION * UU; idx += TPB) {
        int jru = idx >> 5, u = idx & 31;
        int j = j0 + jru;
        if (0 <= j && j < LL)
            s_k[jru * KPAD + u] = k[(size_t)(b * LL + j) * UU + u];
    }
    __syncthreads();

    // Phase 1: 512 e-entries, 2 threads each (16 u per thread)
    {
        int entry = t >> 1, half = t & 1;
        int r = entry >> 7, jr = entry & 127;
        int j = j0 + r + jr;                // band cond == j in [0,LL)
        int jru = r + jr;
        float acc = 0.0f;
        if (0 <= j && j < LL) {
            const float* kp = &s_k[jru * KPAD + half * 16];
            const float* qp = &s_q[r * UU + half * 16];
            const float* wp = &s_wa[half * 16];
            #pragma unroll
            for (int u = 0; u < 16; ++u)
                acc = fmaf(wp[u], fast_tanh(qp[u] + kp[u]), acc);
        }
        acc += __shfl_xor(acc, 1);          // pair shares same j -> uniform guard
        if (half == 0 && 0 <= j && j < LL)
            s_a[r * APAD + jru] = __expf(acc + ba[0]);
    }
    __syncthreads();

    // Phase 2: per-row softmax denominators (4 waves, one per row)
    if (t < 4 * 64) {
        int r = t >> 6, lane = t & 63;
        float v = s_a[r * APAD + lane] + s_a[r * APAD + lane + 64];
        if (lane < APAD - 128) v += s_a[r * APAD + lane + 128];
        #pragma unroll
        for (int off = 32; off > 0; off >>= 1) v += __shfl_xor(v, off);
        if (lane == 0) s_inv[r] = 1.0f / (v + 1e-7f);
    }
    // no barrier needed here: s_inv is consumed only after the next barrier

    // Phase 3: 4 groups of 256 split the union band j-strided;
    // x[j,:] loaded once per block.
    {
        int g = t >> 8, d = t & 255;
        float acc[RPB] = {0.0f, 0.0f, 0.0f, 0.0f};
        const float* xb = x + (size_t)(b * LL) * DD + d;
        for (int jru = g; jru < UNION; jru += 4) {
            int j = j0 + jru;               // wave-uniform guard
            if (0 <= j && j < LL) {
                float xv = xb[(size_t)j * DD];
                #pragma unroll
                for (int r = 0; r < RPB; ++r)
                    acc[r] = fmaf(s_a[r * APAD + jru], xv, acc[r]);
            }
        }
        #pragma unroll
        for (int r = 0; r < RPB; ++r)
            s_part[(g * RPB + r) * DD + d] = acc[r];
    }
    __syncthreads();

    // Final: one thread per output element, reduce 4 partials, normalize
    {
        int r = t >> 8, d = t & 255;
        float v = s_part[(0 * RPB + r) * DD + d]
                + s_part[(1 * RPB + r) * DD + d]
                + s_part[(2 * RPB + r) * DD + d]
                + s_part[(3 * RPB + r) * DD + d];
        out[(size_t)(rowbase + r) * DD + d] = v * s_inv[r];
    }
}

extern "C" void kernel_launch(void* const* d_in, const int* in_sizes, int n_in,
                              void* d_out, int out_size, void* d_ws, size_t ws_size,
                              hipStream_t stream) {
    const float* x  = (const float*)d_in[0];
    const float* Wt = (const float*)d_in[1];
    const float* Wx = (const float*)d_in[2];
    const float* bh = (const float*)d_in[3];
    const float* Wa = (const float*)d_in[4];
    const float* ba = (const float*)d_in[5];
    float* out = (float*)d_out;

    float* q  = (float*)d_ws;                      // B*L*U floats
    float* kk = q + (size_t)BB * LL * UU;          // B*L*U floats

    qk_kernel<<<(BB * LL) / 8, 256, 0, stream>>>(x, Wt, Wx, bh, q, kk);
    attn_kernel<<<(BB * LL) / RPB, TPB, 0, stream>>>(x, q, kk, Wa, ba, out);
}